// Round 1
// baseline (126.231 us; speedup 1.0000x reference)
//
#include <hip/hip_runtime.h>
#include <math.h>

#define NN 1024
#define BTH 256
#define TOPK 3
#define CHUNK 64
#define NCHUNK (NN / CHUNK)

// ---------------------------------------------------------------------------
// Kernel 1: per-batch top-3 of predictions -> mult[b][n] in {1.0, 2.0}
// Tie-break: lower index wins on equal value (matches jax.lax.top_k).
// ---------------------------------------------------------------------------
__global__ void topk_mult_kernel(const float* __restrict__ pred,
                                 float* __restrict__ mult) {
    const int b = blockIdx.x;
    const int t = threadIdx.x;
    __shared__ float s_p[NN];
    __shared__ float s_val[BTH];
    __shared__ int   s_idx[BTH];

    const float* p = pred + (size_t)b * NN;
    for (int n = t; n < NN; n += BTH) {
        s_p[n] = p[n];
        mult[(size_t)b * NN + n] = 1.0f;
    }
    __syncthreads();

    for (int k = 0; k < TOPK; ++k) {
        float bv = -INFINITY;
        int   bi = NN;  // large so "lower index wins" works from the start
        for (int n = t; n < NN; n += BTH) {
            float v = s_p[n];
            if (v > bv || (v == bv && n < bi)) { bv = v; bi = n; }
        }
        s_val[t] = bv;
        s_idx[t] = bi;
        __syncthreads();
        for (int off = BTH / 2; off > 0; off >>= 1) {
            if (t < off) {
                float ov = s_val[t + off];
                int   oi = s_idx[t + off];
                if (ov > s_val[t] || (ov == s_val[t] && oi < s_idx[t])) {
                    s_val[t] = ov; s_idx[t] = oi;
                }
            }
            __syncthreads();
        }
        if (t == 0) {
            int win = s_idx[0];
            mult[(size_t)b * NN + win] = 2.0f;
            s_p[win] = -INFINITY;  // exclude from next round
        }
        __syncthreads();
    }
}

// ---------------------------------------------------------------------------
// Kernel 2: pairwise loss partial sums.
// grid = (NCHUNK, B). Each block: i in [chunk*64, chunk*64+64) x all j.
// Writes deterministic partials psum[b][chunk], pcnt[b][chunk].
// ---------------------------------------------------------------------------
__global__ void __launch_bounds__(BTH)
pairwise_kernel(const float* __restrict__ pred,
                const float* __restrict__ rel,
                const float* __restrict__ mult,
                float* __restrict__ psum,
                float* __restrict__ pcnt) {
    const int chunk = blockIdx.x;
    const int b     = blockIdx.y;
    const int t     = threadIdx.x;

    __shared__ float s_p[NN];
    __shared__ float s_r[NN];
    __shared__ float s_m[NN];

    // Vectorized cooperative load: N/4 = 256 float4 per array = 1 per thread.
    {
        const float4* p4 = (const float4*)(pred + (size_t)b * NN);
        const float4* r4 = (const float4*)(rel  + (size_t)b * NN);
        const float4* m4 = (const float4*)(mult + (size_t)b * NN);
        ((float4*)s_p)[t] = p4[t];
        ((float4*)s_r)[t] = r4[t];
        ((float4*)s_m)[t] = m4[t];
    }
    __syncthreads();

    float acc = 0.0f;
    float cnt = 0.0f;
    const int i0 = chunk * CHUNK;

    for (int ii = 0; ii < CHUNK; ++ii) {
        const int   i  = i0 + ii;
        const float pi = s_p[i];
        const float ri = s_r[i];
        const float mi = s_m[i];
#pragma unroll
        for (int jj = 0; jj < NN / BTH; ++jj) {
            const int   j  = t + jj * BTH;
            const float x  = pi - s_p[j];
            const float rj = s_r[j];
            const float v  = (ri != rj) ? 1.0f : 0.0f;          // valid pair
            const float tg = (ri > rj) ? 1.0f : 0.0f;           // target
            const float w  = mi * s_m[j];                        // lambda weight
            const float ax = fabsf(x);
            // stable softplus: max(x,0) + log1p(exp(-|x|))
            const float sp = fmaxf(x, 0.0f) + log1pf(__expf(-ax));
            acc = fmaf(v * w, sp - tg * x, acc);
            cnt += v;
        }
    }

    // Block reduction: wave shuffle then LDS across the 4 waves.
    for (int off = 32; off > 0; off >>= 1) {
        acc += __shfl_down(acc, off);
        cnt += __shfl_down(cnt, off);
    }
    __shared__ float s_red[8];
    const int wid = t >> 6;
    if ((t & 63) == 0) { s_red[wid] = acc; s_red[4 + wid] = cnt; }
    __syncthreads();
    if (t == 0) {
        const float a = s_red[0] + s_red[1] + s_red[2] + s_red[3];
        const float c = s_red[4] + s_red[5] + s_red[6] + s_red[7];
        psum[(size_t)b * NCHUNK + chunk] = a;
        pcnt[(size_t)b * NCHUNK + chunk] = c;
    }
}

// ---------------------------------------------------------------------------
// Kernel 3: finalize. loss = mean_b( sum_b / (cnt_b + 1e-8) )
// ---------------------------------------------------------------------------
__global__ void finalize_kernel(const float* __restrict__ psum,
                                const float* __restrict__ pcnt,
                                float* __restrict__ out, int B) {
    const int t = threadIdx.x;
    float l = 0.0f;
    if (t < B) {
        float s = 0.0f, c = 0.0f;
        for (int k = 0; k < NCHUNK; ++k) {
            s += psum[(size_t)t * NCHUNK + k];
            c += pcnt[(size_t)t * NCHUNK + k];
        }
        l = s / (c + 1e-8f);
    }
    for (int off = 32; off > 0; off >>= 1) l += __shfl_down(l, off);
    if (t == 0) out[0] = l / (float)B;
}

extern "C" void kernel_launch(void* const* d_in, const int* in_sizes, int n_in,
                              void* d_out, int out_size, void* d_ws, size_t ws_size,
                              hipStream_t stream) {
    const float* pred = (const float*)d_in[0];
    const float* rel  = (const float*)d_in[1];
    float* out = (float*)d_out;

    const int B = in_sizes[0] / NN;  // 32

    // Workspace layout (floats): mult[B*NN] | psum[B*NCHUNK] | pcnt[B*NCHUNK]
    float* mult = (float*)d_ws;
    float* psum = mult + (size_t)B * NN;
    float* pcnt = psum + (size_t)B * NCHUNK;

    topk_mult_kernel<<<B, BTH, 0, stream>>>(pred, mult);
    pairwise_kernel<<<dim3(NCHUNK, B), BTH, 0, stream>>>(pred, rel, mult, psum, pcnt);
    finalize_kernel<<<1, 64, 0, stream>>>(psum, pcnt, out, B);
}

// Round 2
// 33.007 us; speedup vs baseline: 3.8244x; 3.8244x over previous
//
#include <hip/hip_runtime.h>
#include <math.h>

#define NN 1024
#define BTH 256
#define TOPK 3
#define NT 16              // NN/64 chunks per row
#define NTILES 136         // NT*(NT+1)/2 upper-triangle 64x64 tiles

// ---------------------------------------------------------------------------
// Kernel 1: per-batch top-3 -> mult[b][n] in {1,2}; grade histogram ->
// analytic ordered-valid-pair count cntv[b] = N^2 - sum_g c_g^2.
// Tie-break: lower index wins (matches jax.lax.top_k).
// ---------------------------------------------------------------------------
__global__ void topk_mult_kernel(const float* __restrict__ pred,
                                 const float* __restrict__ rel,
                                 float* __restrict__ mult,
                                 float* __restrict__ cntv) {
    const int b = blockIdx.x;
    const int t = threadIdx.x;
    __shared__ float s_p[NN];
    __shared__ float s_val[BTH];
    __shared__ int   s_idx[BTH];
    __shared__ int   s_hist[5];

    if (t < 5) s_hist[t] = 0;
    const float* p = pred + (size_t)b * NN;
    const float* r = rel  + (size_t)b * NN;
    for (int n = t; n < NN; n += BTH) {
        s_p[n] = p[n];
        mult[(size_t)b * NN + n] = 1.0f;
        atomicAdd(&s_hist[(int)r[n]], 1);
    }
    __syncthreads();

    for (int k = 0; k < TOPK; ++k) {
        float bv = -INFINITY;
        int   bi = NN;
        for (int n = t; n < NN; n += BTH) {
            float v = s_p[n];
            if (v > bv || (v == bv && n < bi)) { bv = v; bi = n; }
        }
        s_val[t] = bv;
        s_idx[t] = bi;
        __syncthreads();
        for (int off = BTH / 2; off > 0; off >>= 1) {
            if (t < off) {
                float ov = s_val[t + off];
                int   oi = s_idx[t + off];
                if (ov > s_val[t] || (ov == s_val[t] && oi < s_idx[t])) {
                    s_val[t] = ov; s_idx[t] = oi;
                }
            }
            __syncthreads();
        }
        if (t == 0) {
            int win = s_idx[0];
            mult[(size_t)b * NN + win] = 2.0f;
            s_p[win] = -INFINITY;
        }
        __syncthreads();
    }

    if (t == 0) {
        int s2 = 0;
        for (int g = 0; g < 5; ++g) s2 += s_hist[g] * s_hist[g];
        cntv[b] = (float)(NN * NN - s2);
    }
}

// ---------------------------------------------------------------------------
// Kernel 2: upper-triangle 64x64 tiles; one wave per tile, 4 tiles/block.
// Lane l owns column j = j0+l in registers; rows broadcast from LDS.
// Pair symmetry: (i,j)+(j,i) contributions are equal -> compute j>i, x2.
// ---------------------------------------------------------------------------
__global__ void __launch_bounds__(BTH)
tile_kernel(const float* __restrict__ pred,
            const float* __restrict__ rel,
            const float* __restrict__ mult,
            float* __restrict__ psum) {
    const int b = blockIdx.y;
    const int t = threadIdx.x;
    const int w = t >> 6;
    const int l = t & 63;
    const int L = blockIdx.x * 4 + w;   // tile id, 0..135 (grid.x == 34)

    // decode L -> (ti, tj), tj >= ti
    int rem = L, ti = 0;
    while (rem >= NT - ti) { rem -= NT - ti; ++ti; }
    const int tj = ti + rem;

    __shared__ float s_i[4][3][64];     // per-wave row segment: p, r, m

    const size_t base = (size_t)b * NN;
    const int i0 = ti * 64, j0 = tj * 64;

    s_i[w][0][l] = pred[base + i0 + l];
    s_i[w][1][l] = rel [base + i0 + l];
    s_i[w][2][l] = mult[base + i0 + l];
    const float jp = pred[base + j0 + l];
    const float jr = rel [base + j0 + l];
    const float jm = mult[base + j0 + l];
    __syncthreads();

    float acc = 0.0f;
    const bool diag = (ti == tj);

#pragma unroll 16
    for (int ii = 0; ii < 64; ++ii) {
        const float pi = s_i[w][0][ii];
        const float ri = s_i[w][1][ii];
        const float mi = s_i[w][2][ii];
        const float x  = pi - jp;
        // stable softplus via HW exp2/log2 paths
        const float e  = __expf(-fabsf(x));
        const float sp = fmaxf(x, 0.0f) + __logf(1.0f + e);
        const float s2 = (ri > jr) ? (sp - x) : sp;       // sp - t*x
        const bool keep = (ri != jr) && (!diag || l > ii);
        const float wv = keep ? mi * jm : 0.0f;
        acc = fmaf(wv, s2, acc);
    }

    for (int off = 32; off > 0; off >>= 1) acc += __shfl_down(acc, off);
    if (l == 0) psum[(size_t)b * NTILES + L] = acc * 2.0f;  // both pair orders
}

// ---------------------------------------------------------------------------
// Kernel 3: finalize. loss = mean_b( psum_b / (cnt_b + 1e-8) )
// 256 threads: 8 lanes per batch sum the 136 tile partials.
// ---------------------------------------------------------------------------
__global__ void finalize_kernel(const float* __restrict__ psum,
                                const float* __restrict__ cntv,
                                float* __restrict__ out, int B) {
    const int t = threadIdx.x;
    const int b = t >> 3;
    const int k = t & 7;
    __shared__ float s_l[32];

    float s = 0.0f;
    for (int e = k; e < NTILES; e += 8) s += psum[(size_t)b * NTILES + e];
    s += __shfl_xor(s, 1);
    s += __shfl_xor(s, 2);
    s += __shfl_xor(s, 4);
    if (k == 0) s_l[b] = s / (cntv[b] + 1e-8f);
    __syncthreads();
    if (t == 0) {
        float m = 0.0f;
        for (int i = 0; i < B; ++i) m += s_l[i];
        out[0] = m / (float)B;
    }
}

extern "C" void kernel_launch(void* const* d_in, const int* in_sizes, int n_in,
                              void* d_out, int out_size, void* d_ws, size_t ws_size,
                              hipStream_t stream) {
    const float* pred = (const float*)d_in[0];
    const float* rel  = (const float*)d_in[1];
    float* out = (float*)d_out;

    const int B = in_sizes[0] / NN;  // 32

    // Workspace (floats): mult[B*NN] | psum[B*NTILES] | cntv[B]
    float* mult = (float*)d_ws;
    float* psum = mult + (size_t)B * NN;
    float* cntv = psum + (size_t)B * NTILES;

    topk_mult_kernel<<<B, BTH, 0, stream>>>(pred, rel, mult, cntv);
    tile_kernel<<<dim3(NTILES / 4, B), BTH, 0, stream>>>(pred, rel, mult, psum);
    finalize_kernel<<<1, BTH, 0, stream>>>(psum, cntv, out, B);
}